// Round 5
// baseline (467.469 us; speedup 1.0000x reference)
//
#include <hip/hip_runtime.h>
#include <hip/hip_bf16.h>

// DeeperGCN round-4: (1) u16 edge pipeline - k_hist caches src16/dst16, scatter
// writes u16 eSrc (halves write-allocate traffic, 55MB->~28MB); (2) fuse agg
// into mlp (k_aggmlp): wave aggregates its 16-node tile into the LDS A-frag
// region, killing the AGbf global round-trip + 2 launches.

#define NN 50000
#define EE 800000
#define FIN 128
#define HD 64
#define NB 196  // scan blocks: 196*256 = 50176 >= NN+1

typedef unsigned short u16;
typedef unsigned int u32;
using bf16x8 = __attribute__((ext_vector_type(8))) short;
using f32x4 = __attribute__((ext_vector_type(4))) float;

__device__ __forceinline__ float bf2f(u16 u) {
    u32 x = ((u32)u) << 16;
    float f;
    __builtin_memcpy(&f, &x, 4);
    return f;
}
__device__ __forceinline__ short f2bf(float f) {
    u32 u;
    __builtin_memcpy(&u, &f, 4);
    u32 r = (u + 0x7fffu + ((u >> 16) & 1u)) >> 16;  // RNE
    return (short)r;
}
__device__ __forceinline__ float wredsum(float v) {
#pragma unroll
    for (int m = 32; m >= 1; m >>= 1) v += __shfl_xor(v, m, 64);
    return v;
}

// ---------------- edge_index layout probe + cnt zeroing ----------------
__global__ __launch_bounds__(256) void k_detect(const int* __restrict__ ei,
                                                int* __restrict__ flag,
                                                int* __restrict__ cnt) {
    int i = blockIdx.x * 256 + threadIdx.x;
    if (i < 1024 && ei[2 * i + 1] != 0) atomicExch(flag, 1);  // 1 => int32 layout
    if (i < NN) cnt[i] = 0;
}
__device__ __forceinline__ int eidx_src(const int* ei, int e, int is32) {
    return is32 ? ei[e] : ei[2 * e];
}
__device__ __forceinline__ int eidx_dst(const int* ei, int e, int is32) {
    return is32 ? ei[EE + e] : ei[2 * (EE + e)];
}

// ---------------- CSR build ----------------
__global__ void k_hist(const int* __restrict__ ei, const int* __restrict__ flag,
                       int* __restrict__ cnt, u16* __restrict__ src16,
                       u16* __restrict__ dst16) {
    int e = blockIdx.x * blockDim.x + threadIdx.x;
    if (e >= EE) return;
    int is32 = *flag;
    int s = eidx_src(ei, e, is32);
    int d = eidx_dst(ei, e, is32);
    src16[e] = (u16)s;
    dst16[e] = (u16)d;
    atomicAdd(&cnt[d], 1);
}

__global__ __launch_bounds__(256) void k_scan1(const int* __restrict__ cnt,
                                               int* __restrict__ rowptr,
                                               int* __restrict__ bsum) {
    __shared__ int ts[256];
    int t = threadIdx.x;
    int idx = blockIdx.x * 256 + t;
    int v = (idx < NN) ? cnt[idx] : 0;
    ts[t] = v;
    __syncthreads();
#pragma unroll
    for (int d = 1; d < 256; d <<= 1) {
        int u = (t >= d) ? ts[t - d] : 0;
        __syncthreads();
        ts[t] += u;
        __syncthreads();
    }
    if (idx <= NN) rowptr[idx] = ts[t] - v;
    if (t == 255) bsum[blockIdx.x] = ts[255];
}

__global__ __launch_bounds__(256) void k_scan2(int* __restrict__ bsum) {
    __shared__ int ts[256];
    int t = threadIdx.x;
    int v = (t < NB) ? bsum[t] : 0;
    ts[t] = v;
    __syncthreads();
#pragma unroll
    for (int d = 1; d < 256; d <<= 1) {
        int u = (t >= d) ? ts[t - d] : 0;
        __syncthreads();
        ts[t] += u;
        __syncthreads();
    }
    if (t < NB) bsum[t] = ts[t] - v;
}

__global__ __launch_bounds__(256) void k_scan3(const int* __restrict__ bsum,
                                               int* __restrict__ rowptr,
                                               int* __restrict__ cnt) {
    int idx = blockIdx.x * 256 + threadIdx.x;
    if (idx <= NN) rowptr[idx] += bsum[blockIdx.x];
    if (idx < NN) cnt[idx] = 0;
}

__global__ void k_scatter(const u16* __restrict__ src16, const u16* __restrict__ dst16,
                          const int* __restrict__ rowptr, int* __restrict__ cnt,
                          u16* __restrict__ eSrc) {
    int e = blockIdx.x * blockDim.x + threadIdx.x;
    if (e >= EE) return;
    int d = dst16[e];
    int p = atomicAdd(&cnt[d], 1);
    eSrc[rowptr[d] + p] = src16[e];
}

// ---------------- encoder (MFMA): Abf[n,0:64] = bf16(x[n,0:128] @ encW + encB) ----------------
__global__ __launch_bounds__(256) void k_enc(const float* __restrict__ x,
                                             const float* __restrict__ W,
                                             const float* __restrict__ b,
                                             u16* __restrict__ Abf) {
    __shared__ short wtE[64 * 136];
    int tid = threadIdx.x;
    for (int i = tid; i < FIN * HD; i += 256) wtE[(i & 63) * 136 + (i >> 6)] = f2bf(W[i]);
    __syncthreads();

    int lane = tid & 63, wid = tid >> 6;
    int l16 = lane & 15, q = lane >> 4;
    int m0 = blockIdx.x * 64 + wid * 16;
    int mrow = m0 + l16;
    if (mrow >= NN) mrow = NN - 1;

    bf16x8 af[4];
#pragma unroll
    for (int c = 0; c < 4; c++) {
        const float4* p = (const float4*)(x + (size_t)mrow * FIN + c * 32 + q * 8);
        float4 p0 = p[0], p1 = p[1];
        af[c][0] = f2bf(p0.x); af[c][1] = f2bf(p0.y); af[c][2] = f2bf(p0.z); af[c][3] = f2bf(p0.w);
        af[c][4] = f2bf(p1.x); af[c][5] = f2bf(p1.y); af[c][6] = f2bf(p1.z); af[c][7] = f2bf(p1.w);
    }
    f32x4 acc[4];
#pragma unroll
    for (int u = 0; u < 4; u++) {
        f32x4 z = {0.f, 0.f, 0.f, 0.f};
#pragma unroll
        for (int c = 0; c < 4; c++) {
            bf16x8 wf = *(const bf16x8*)(const void*)&wtE[(u * 16 + l16) * 136 + c * 32 + q * 8];
            z = __builtin_amdgcn_mfma_f32_16x16x32_bf16(af[c], wf, z, 0, 0, 0);
        }
        acc[u] = z;
    }
#pragma unroll
    for (int u = 0; u < 4; u++) {
        int col = u * 16 + l16;
        float bc = b[col];
#pragma unroll
        for (int r = 0; r < 4; r++) {
            int node = m0 + q * 4 + r;
            if (node < NN) Abf[(size_t)node * HD + col] = (u16)f2bf(acc[u][r] + bc);
        }
    }
}

// ---------------- fused GENConv: softmax-agg (per-wave tile) + MFMA MLP ----------------
__global__ __launch_bounds__(256) void k_aggmlp(const u16* __restrict__ Xbf,
                                                const float* __restrict__ Xfp,  // self (may be null)
                                                const int* __restrict__ rowptr,
                                                const u16* __restrict__ eSrc,
                                                const float* __restrict__ tptr,
                                                const float* __restrict__ W1,
                                                const float* __restrict__ B1,
                                                const float* __restrict__ G1,
                                                const float* __restrict__ BE1,
                                                const float* __restrict__ W2,
                                                const float* __restrict__ B2,
                                                float* __restrict__ OUTfp,  // may be null
                                                u16* __restrict__ OUTbf) {
    __shared__ short wt1[128 * 72];      // W1T[j][k]
    __shared__ short wt2[64 * 136];      // W2T[c][k]
    __shared__ short hregion[64 * 136];  // cols 0..63: agg A-tile; later cols 0..127: H
    int tid = threadIdx.x;
    for (int i = tid; i < HD * 128; i += 256) wt1[(i & 127) * 72 + (i >> 7)] = f2bf(W1[i]);
    for (int i = tid; i < 128 * HD; i += 256) wt2[(i & 63) * 136 + (i >> 6)] = f2bf(W2[i]);
    __syncthreads();

    int lane = tid & 63, wid = tid >> 6;
    int l16 = lane & 15, q = lane >> 4;
    int m0 = blockIdx.x * 64 + wid * 16;
    float tt = tptr[0];

    // ---- aggregation: wave owns 16 nodes, lane = channel ----
    for (int i = 0; i < 16; i++) {
        int n = m0 + i;
        if (n >= NN) n = NN - 1;  // tail dup; stores masked later
        int s = rowptr[n], e = rowptr[n + 1];
        float selfv = Xfp ? Xfp[(size_t)n * HD + lane] : bf2f(Xbf[(size_t)n * HD + lane]);
        float num = 0.f, den = 0.f;
        int k = s;
        for (; k + 7 < e; k += 8) {
            int sv[8];
#pragma unroll
            for (int u = 0; u < 8; u++) sv[u] = eSrc[k + u];
            float v[8];
#pragma unroll
            for (int u = 0; u < 8; u++) v[u] = bf2f(Xbf[(size_t)sv[u] * HD + lane]);
#pragma unroll
            for (int u = 0; u < 8; u++) {
                float m = fmaxf(v[u], 0.f) + 1e-7f;
                float p = __expf(m * tt);
                den += p;
                num += m * p;
            }
        }
        for (; k < e; k++) {
            float v = bf2f(Xbf[(size_t)eSrc[k] * HD + lane]);
            float m = fmaxf(v, 0.f) + 1e-7f;
            float p = __expf(m * tt);
            den += p;
            num += m * p;
        }
        float val = num / (den + 1e-16f) + selfv;
        hregion[(wid * 16 + i) * 136 + lane] = f2bf(val);
    }
    // wave-private rows; DS ops complete in-order per wave -> safe to read back

    float b1v[8], g1v[8], bev[8];
#pragma unroll
    for (int tl = 0; tl < 8; tl++) {
        int j = tl * 16 + l16;
        b1v[tl] = B1[j];
        g1v[tl] = G1[j];
        bev[tl] = BE1[j];
    }

    // GEMM1: [16x64] @ [64x128]
    bf16x8 a0 = *(const bf16x8*)(const void*)&hregion[(wid * 16 + l16) * 136 + q * 8];
    bf16x8 a1 = *(const bf16x8*)(const void*)&hregion[(wid * 16 + l16) * 136 + 32 + q * 8];
    f32x4 acc1[8];
#pragma unroll
    for (int tl = 0; tl < 8; tl++) {
        bf16x8 w0 = *(const bf16x8*)(const void*)&wt1[(tl * 16 + l16) * 72 + q * 8];
        bf16x8 w1 = *(const bf16x8*)(const void*)&wt1[(tl * 16 + l16) * 72 + 32 + q * 8];
        f32x4 z = {0.f, 0.f, 0.f, 0.f};
        z = __builtin_amdgcn_mfma_f32_16x16x32_bf16(a0, w0, z, 0, 0, 0);
        z = __builtin_amdgcn_mfma_f32_16x16x32_bf16(a1, w1, z, 0, 0, 0);
        acc1[tl] = z;
    }
    __syncthreads();  // all A-tile reads done before hregion is overwritten with H

    // bias + LN(128) + relu
    float S[4] = {0, 0, 0, 0}, Q[4] = {0, 0, 0, 0};
#pragma unroll
    for (int tl = 0; tl < 8; tl++)
#pragma unroll
        for (int r = 0; r < 4; r++) {
            float v = acc1[tl][r] + b1v[tl];
            acc1[tl][r] = v;
            S[r] += v;
            Q[r] += v * v;
        }
#pragma unroll
    for (int m = 8; m >= 1; m >>= 1)
#pragma unroll
        for (int r = 0; r < 4; r++) {
            S[r] += __shfl_xor(S[r], m, 64);
            Q[r] += __shfl_xor(Q[r], m, 64);
        }
    float mu[4], rs[4];
#pragma unroll
    for (int r = 0; r < 4; r++) {
        mu[r] = S[r] * (1.f / 128.f);
        float var = Q[r] * (1.f / 128.f) - mu[r] * mu[r];
        rs[r] = rsqrtf(var + 1e-5f);
    }
#pragma unroll
    for (int tl = 0; tl < 8; tl++)
#pragma unroll
        for (int r = 0; r < 4; r++) {
            float h = fmaxf((acc1[tl][r] - mu[r]) * rs[r] * g1v[tl] + bev[tl], 0.f);
            hregion[(wid * 16 + q * 4 + r) * 136 + tl * 16 + l16] = f2bf(h);
        }

    // GEMM2: [16x128] @ [128x64]
    bf16x8 a2[4];
#pragma unroll
    for (int c = 0; c < 4; c++)
        a2[c] = *(const bf16x8*)(const void*)&hregion[(wid * 16 + l16) * 136 + c * 32 + q * 8];
    f32x4 acc2[4];
#pragma unroll
    for (int u = 0; u < 4; u++) {
        f32x4 z = {0.f, 0.f, 0.f, 0.f};
#pragma unroll
        for (int c = 0; c < 4; c++) {
            bf16x8 wf = *(const bf16x8*)(const void*)&wt2[(u * 16 + l16) * 136 + c * 32 + q * 8];
            z = __builtin_amdgcn_mfma_f32_16x16x32_bf16(a2[c], wf, z, 0, 0, 0);
        }
        acc2[u] = z;
    }
#pragma unroll
    for (int u = 0; u < 4; u++) {
        int col = u * 16 + l16;
        float bc = B2[col];
#pragma unroll
        for (int r = 0; r < 4; r++) {
            int node = m0 + q * 4 + r;
            if (node < NN) {
                float val = acc2[u][r] + bc;
                if (OUTfp) OUTfp[(size_t)node * HD + col] = val;
                OUTbf[(size_t)node * HD + col] = (u16)f2bf(val);
            }
        }
    }
}

// ---------------- fused tail ----------------
__global__ __launch_bounds__(256) void k_final(const float* __restrict__ X1,
                                               const u16* __restrict__ H2bf,
                                               const float* __restrict__ LG,
                                               const float* __restrict__ LB,
                                               const float* __restrict__ NG,
                                               const float* __restrict__ NB_,
                                               const float* __restrict__ LW,
                                               const float* __restrict__ LBias,
                                               float* __restrict__ out) {
    int t = threadIdx.x;
    int lane = t & 63, wid = t >> 6;
    int n = blockIdx.x * 4 + wid;
    if (n >= NN) return;
    float x1v = X1[(size_t)n * HD + lane];
    float h2v = bf2f(H2bf[(size_t)n * HD + lane]);
    float s = wredsum(h2v);
    float qq = wredsum(h2v * h2v);
    float mu = s * (1.f / 64.f);
    float var = qq * (1.f / 64.f) - mu * mu;
    float hn = fmaxf((h2v - mu) * rsqrtf(var + 1e-5f) * LG[lane] + LB[lane], 0.f);
    float s2 = wredsum(x1v + hn);
    float q2 = wredsum(x1v * x1v + hn * hn);
    float mu2 = s2 * (1.f / 128.f);
    float var2 = q2 * (1.f / 128.f) - mu2 * mu2;
    float rs2 = rsqrtf(var2 + 1e-5f);
    float av = fmaxf((x1v - mu2) * rs2 * NG[lane] + NB_[lane], 0.f);
    float bv = fmaxf((hn - mu2) * rs2 * NG[64 + lane] + NB_[64 + lane], 0.f);
    float acc = av * LW[lane] + bv * LW[64 + lane];
    float tot = wredsum(acc);
    if (lane == 0) out[n] = tot + LBias[0];
}

extern "C" void kernel_launch(void* const* d_in, const int* in_sizes, int n_in,
                              void* d_out, int out_size, void* d_ws, size_t ws_size,
                              hipStream_t stream) {
    const float* x = (const float*)d_in[0];
    const int* ei = (const int*)d_in[1];
    const float* encW = (const float*)d_in[2];
    const float* encB = (const float*)d_in[3];
    const float* tptr = (const float*)d_in[4];
    const float* cW1 = (const float*)d_in[5];
    const float* cB1 = (const float*)d_in[6];
    const float* cG1 = (const float*)d_in[7];
    const float* cBE1 = (const float*)d_in[8];
    const float* cW2 = (const float*)d_in[9];
    const float* cB2 = (const float*)d_in[10];
    const float* ln1g = (const float*)d_in[11];
    const float* ln1b = (const float*)d_in[12];
    const float* ng = (const float*)d_in[13];
    const float* nb = (const float*)d_in[14];
    const float* lw = (const float*)d_in[15];
    const float* lb = (const float*)d_in[16];

    char* w = (char*)d_ws;
    size_t off = 0;
    auto carve = [&](size_t bytes) {
        void* p = w + off;
        off += (bytes + 255) & ~(size_t)255;
        return p;
    };
    int* flag = (int*)carve(4);
    int* rowptr = (int*)carve((NN + 1) * 4);
    int* cnt = (int*)carve((size_t)NN * 4);
    int* bsum = (int*)carve(NB * 4);
    u16* src16 = (u16*)carve((size_t)EE * 2);
    u16* dst16 = (u16*)carve((size_t)EE * 2);
    u16* eSrc = (u16*)carve((size_t)EE * 2);
    u16* Abf = (u16*)carve((size_t)NN * HD * 2);
    float* X1 = (float*)carve((size_t)NN * HD * 4);
    u16* X1bf = (u16*)carve((size_t)NN * HD * 2);
    u16* H2bf = Abf;  // Abf dead after conv1

    hipMemsetAsync(flag, 0, 4, stream);
    k_detect<<<NB, 256, 0, stream>>>(ei, flag, cnt);  // probes layout + zeroes cnt
    k_hist<<<(EE + 255) / 256, 256, 0, stream>>>(ei, flag, cnt, src16, dst16);
    k_scan1<<<NB, 256, 0, stream>>>(cnt, rowptr, bsum);
    k_scan2<<<1, 256, 0, stream>>>(bsum);
    k_scan3<<<NB, 256, 0, stream>>>(bsum, rowptr, cnt);  // also re-zeroes cnt
    k_scatter<<<(EE + 255) / 256, 256, 0, stream>>>(src16, dst16, rowptr, cnt, eSrc);

    const int GB = (NN + 63) / 64;  // 782
    k_enc<<<GB, 256, 0, stream>>>(x, encW, encB, Abf);

    // conv1 (agg + MLP fused)
    k_aggmlp<<<GB, 256, 0, stream>>>(Abf, nullptr, rowptr, eSrc, tptr, cW1, cB1, cG1, cBE1,
                                     cW2, cB2, X1, X1bf);
    // conv2 (shared weights)
    k_aggmlp<<<GB, 256, 0, stream>>>(X1bf, X1, rowptr, eSrc, tptr, cW1, cB1, cG1, cBE1,
                                     cW2, cB2, nullptr, H2bf);

    k_final<<<(NN + 3) / 4, 256, 0, stream>>>(X1, H2bf, ln1g, ln1b, ng, nb, lw, lb,
                                              (float*)d_out);
}

// Round 6
// 325.620 us; speedup vs baseline: 1.4356x; 1.4356x over previous
//
#include <hip/hip_runtime.h>
#include <hip/hip_bf16.h>

// DeeperGCN round-5: revert round-4 fusion (k_aggmlp serialized the latency-bound
// gather at 17% occupancy: 128us vs ~60us split). Back to round-3 structure
// (k_agg @2048 blocks high-occupancy + k_mlp MFMA @782), keeping round-4's u16
// edge pipeline (src16/dst16 cache, u16 eSrc scatter) and fused cnt-zeroing.

#define NN 50000
#define EE 800000
#define FIN 128
#define HD 64
#define NB 196  // scan blocks: 196*256 = 50176 >= NN+1

typedef unsigned short u16;
typedef unsigned int u32;
using bf16x8 = __attribute__((ext_vector_type(8))) short;
using f32x4 = __attribute__((ext_vector_type(4))) float;

__device__ __forceinline__ float bf2f(u16 u) {
    u32 x = ((u32)u) << 16;
    float f;
    __builtin_memcpy(&f, &x, 4);
    return f;
}
__device__ __forceinline__ short f2bf(float f) {
    u32 u;
    __builtin_memcpy(&u, &f, 4);
    u32 r = (u + 0x7fffu + ((u >> 16) & 1u)) >> 16;  // RNE
    return (short)r;
}
__device__ __forceinline__ float wredsum(float v) {
#pragma unroll
    for (int m = 32; m >= 1; m >>= 1) v += __shfl_xor(v, m, 64);
    return v;
}

// ---------------- edge_index layout probe + cnt zeroing ----------------
__global__ __launch_bounds__(256) void k_detect(const int* __restrict__ ei,
                                                int* __restrict__ flag,
                                                int* __restrict__ cnt) {
    int i = blockIdx.x * 256 + threadIdx.x;
    if (i < 1024 && ei[2 * i + 1] != 0) atomicExch(flag, 1);  // 1 => int32 layout
    if (i < NN) cnt[i] = 0;
}
__device__ __forceinline__ int eidx_src(const int* ei, int e, int is32) {
    return is32 ? ei[e] : ei[2 * e];
}
__device__ __forceinline__ int eidx_dst(const int* ei, int e, int is32) {
    return is32 ? ei[EE + e] : ei[2 * (EE + e)];
}

// ---------------- CSR build ----------------
__global__ void k_hist(const int* __restrict__ ei, const int* __restrict__ flag,
                       int* __restrict__ cnt, u16* __restrict__ src16,
                       u16* __restrict__ dst16) {
    int e = blockIdx.x * blockDim.x + threadIdx.x;
    if (e >= EE) return;
    int is32 = *flag;
    int s = eidx_src(ei, e, is32);
    int d = eidx_dst(ei, e, is32);
    src16[e] = (u16)s;
    dst16[e] = (u16)d;
    atomicAdd(&cnt[d], 1);
}

__global__ __launch_bounds__(256) void k_scan1(const int* __restrict__ cnt,
                                               int* __restrict__ rowptr,
                                               int* __restrict__ bsum) {
    __shared__ int ts[256];
    int t = threadIdx.x;
    int idx = blockIdx.x * 256 + t;
    int v = (idx < NN) ? cnt[idx] : 0;
    ts[t] = v;
    __syncthreads();
#pragma unroll
    for (int d = 1; d < 256; d <<= 1) {
        int u = (t >= d) ? ts[t - d] : 0;
        __syncthreads();
        ts[t] += u;
        __syncthreads();
    }
    if (idx <= NN) rowptr[idx] = ts[t] - v;
    if (t == 255) bsum[blockIdx.x] = ts[255];
}

__global__ __launch_bounds__(256) void k_scan2(int* __restrict__ bsum) {
    __shared__ int ts[256];
    int t = threadIdx.x;
    int v = (t < NB) ? bsum[t] : 0;
    ts[t] = v;
    __syncthreads();
#pragma unroll
    for (int d = 1; d < 256; d <<= 1) {
        int u = (t >= d) ? ts[t - d] : 0;
        __syncthreads();
        ts[t] += u;
        __syncthreads();
    }
    if (t < NB) bsum[t] = ts[t] - v;
}

__global__ __launch_bounds__(256) void k_scan3(const int* __restrict__ bsum,
                                               int* __restrict__ rowptr,
                                               int* __restrict__ cnt) {
    int idx = blockIdx.x * 256 + threadIdx.x;
    if (idx <= NN) rowptr[idx] += bsum[blockIdx.x];
    if (idx < NN) cnt[idx] = 0;
}

__global__ void k_scatter(const u16* __restrict__ src16, const u16* __restrict__ dst16,
                          const int* __restrict__ rowptr, int* __restrict__ cnt,
                          u16* __restrict__ eSrc) {
    int e = blockIdx.x * blockDim.x + threadIdx.x;
    if (e >= EE) return;
    int d = dst16[e];
    int p = atomicAdd(&cnt[d], 1);
    eSrc[rowptr[d] + p] = src16[e];
}

// ---------------- encoder (MFMA): Abf[n,0:64] = bf16(x[n,0:128] @ encW + encB) ----------------
__global__ __launch_bounds__(256) void k_enc(const float* __restrict__ x,
                                             const float* __restrict__ W,
                                             const float* __restrict__ b,
                                             u16* __restrict__ Abf) {
    __shared__ short wtE[64 * 136];
    int tid = threadIdx.x;
    for (int i = tid; i < FIN * HD; i += 256) wtE[(i & 63) * 136 + (i >> 6)] = f2bf(W[i]);
    __syncthreads();

    int lane = tid & 63, wid = tid >> 6;
    int l16 = lane & 15, q = lane >> 4;
    int m0 = blockIdx.x * 64 + wid * 16;
    int mrow = m0 + l16;
    if (mrow >= NN) mrow = NN - 1;

    bf16x8 af[4];
#pragma unroll
    for (int c = 0; c < 4; c++) {
        const float4* p = (const float4*)(x + (size_t)mrow * FIN + c * 32 + q * 8);
        float4 p0 = p[0], p1 = p[1];
        af[c][0] = f2bf(p0.x); af[c][1] = f2bf(p0.y); af[c][2] = f2bf(p0.z); af[c][3] = f2bf(p0.w);
        af[c][4] = f2bf(p1.x); af[c][5] = f2bf(p1.y); af[c][6] = f2bf(p1.z); af[c][7] = f2bf(p1.w);
    }
    f32x4 acc[4];
#pragma unroll
    for (int u = 0; u < 4; u++) {
        f32x4 z = {0.f, 0.f, 0.f, 0.f};
#pragma unroll
        for (int c = 0; c < 4; c++) {
            bf16x8 wf = *(const bf16x8*)(const void*)&wtE[(u * 16 + l16) * 136 + c * 32 + q * 8];
            z = __builtin_amdgcn_mfma_f32_16x16x32_bf16(af[c], wf, z, 0, 0, 0);
        }
        acc[u] = z;
    }
#pragma unroll
    for (int u = 0; u < 4; u++) {
        int col = u * 16 + l16;
        float bc = b[col];
#pragma unroll
        for (int r = 0; r < 4; r++) {
            int node = m0 + q * 4 + r;
            if (node < NN) Abf[(size_t)node * HD + col] = (u16)f2bf(acc[u][r] + bc);
        }
    }
}

// ---------------- GENConv softmax aggregation (bf16 gather, lane=channel, unroll x8) --------
__global__ __launch_bounds__(256) void k_agg(const u16* __restrict__ Xbf,
                                             const float* __restrict__ Xfp,  // self (may be null)
                                             const int* __restrict__ rowptr,
                                             const u16* __restrict__ eSrc,
                                             const float* __restrict__ tptr,
                                             u16* __restrict__ OUTbf) {
    int t = threadIdx.x;
    int lane = t & 63, wid = t >> 6;
    float tt = tptr[0];
    for (int n = blockIdx.x * 4 + wid; n < NN; n += gridDim.x * 4) {
        int s = rowptr[n], e = rowptr[n + 1];
        float xv = Xfp ? Xfp[(size_t)n * HD + lane] : bf2f(Xbf[(size_t)n * HD + lane]);
        float num = 0.f, den = 0.f;
        int i = s;
        for (; i + 7 < e; i += 8) {
            int sv[8];
#pragma unroll
            for (int k = 0; k < 8; k++) sv[k] = eSrc[i + k];
            float v[8];
#pragma unroll
            for (int k = 0; k < 8; k++) v[k] = bf2f(Xbf[(size_t)sv[k] * HD + lane]);
#pragma unroll
            for (int k = 0; k < 8; k++) {
                float m = fmaxf(v[k], 0.f) + 1e-7f;
                float p = __expf(m * tt);
                den += p;
                num += m * p;
            }
        }
        for (; i < e; i++) {
            float v = bf2f(Xbf[(size_t)eSrc[i] * HD + lane]);
            float m = fmaxf(v, 0.f) + 1e-7f;
            float p = __expf(m * tt);
            den += p;
            num += m * p;
        }
        float agg = num / (den + 1e-16f);
        OUTbf[(size_t)n * HD + lane] = (u16)f2bf(agg + xv);
    }
}

// ---------------- fused MLP (MFMA): relu(LN(in@W1+b1))@W2+b2 ----------------
__global__ __launch_bounds__(256) void k_mlp(const u16* __restrict__ INbf,
                                             const float* __restrict__ W1,
                                             const float* __restrict__ B1,
                                             const float* __restrict__ G1,
                                             const float* __restrict__ BE1,
                                             const float* __restrict__ W2,
                                             const float* __restrict__ B2,
                                             float* __restrict__ OUTfp,  // may be null
                                             u16* __restrict__ OUTbf) {
    __shared__ short wt1[128 * 72];   // W1T[j][k], k 64->72
    __shared__ short wt2[64 * 136];   // W2T[c][k], k 128->136
    __shared__ short hbuf[64 * 136];  // per-wave 16x128 H, row pad 136
    int tid = threadIdx.x;
    for (int i = tid; i < HD * 128; i += 256) wt1[(i & 127) * 72 + (i >> 7)] = f2bf(W1[i]);
    for (int i = tid; i < 128 * HD; i += 256) wt2[(i & 63) * 136 + (i >> 6)] = f2bf(W2[i]);
    __syncthreads();

    int lane = tid & 63, wid = tid >> 6;
    int l16 = lane & 15, q = lane >> 4;
    int m0 = blockIdx.x * 64 + wid * 16;
    int mrow = m0 + l16;
    if (mrow >= NN) mrow = NN - 1;

    float b1v[8], g1v[8], bev[8];
#pragma unroll
    for (int tl = 0; tl < 8; tl++) {
        int j = tl * 16 + l16;
        b1v[tl] = B1[j];
        g1v[tl] = G1[j];
        bev[tl] = BE1[j];
    }

    // GEMM1: [16x64] @ [64x128]
    bf16x8 a0 = *(const bf16x8*)(const void*)(INbf + (size_t)mrow * HD + q * 8);
    bf16x8 a1 = *(const bf16x8*)(const void*)(INbf + (size_t)mrow * HD + 32 + q * 8);
    f32x4 acc1[8];
#pragma unroll
    for (int tl = 0; tl < 8; tl++) {
        bf16x8 w0 = *(const bf16x8*)(const void*)&wt1[(tl * 16 + l16) * 72 + q * 8];
        bf16x8 w1 = *(const bf16x8*)(const void*)&wt1[(tl * 16 + l16) * 72 + 32 + q * 8];
        f32x4 z = {0.f, 0.f, 0.f, 0.f};
        z = __builtin_amdgcn_mfma_f32_16x16x32_bf16(a0, w0, z, 0, 0, 0);
        z = __builtin_amdgcn_mfma_f32_16x16x32_bf16(a1, w1, z, 0, 0, 0);
        acc1[tl] = z;
    }
    // bias + LN(128) + relu
    float S[4] = {0, 0, 0, 0}, Q[4] = {0, 0, 0, 0};
#pragma unroll
    for (int tl = 0; tl < 8; tl++)
#pragma unroll
        for (int r = 0; r < 4; r++) {
            float v = acc1[tl][r] + b1v[tl];
            acc1[tl][r] = v;
            S[r] += v;
            Q[r] += v * v;
        }
#pragma unroll
    for (int m = 8; m >= 1; m >>= 1)
#pragma unroll
        for (int r = 0; r < 4; r++) {
            S[r] += __shfl_xor(S[r], m, 64);
            Q[r] += __shfl_xor(Q[r], m, 64);
        }
    float mu[4], rs[4];
#pragma unroll
    for (int r = 0; r < 4; r++) {
        mu[r] = S[r] * (1.f / 128.f);
        float var = Q[r] * (1.f / 128.f) - mu[r] * mu[r];
        rs[r] = rsqrtf(var + 1e-5f);
    }
#pragma unroll
    for (int tl = 0; tl < 8; tl++)
#pragma unroll
        for (int r = 0; r < 4; r++) {
            float h = fmaxf((acc1[tl][r] - mu[r]) * rs[r] * g1v[tl] + bev[tl], 0.f);
            hbuf[(wid * 16 + q * 4 + r) * 136 + tl * 16 + l16] = f2bf(h);
        }
    // wave-private LDS region: compiler orders via lgkmcnt, no barrier needed

    // GEMM2: [16x128] @ [128x64]
    bf16x8 a2[4];
#pragma unroll
    for (int c = 0; c < 4; c++)
        a2[c] = *(const bf16x8*)(const void*)&hbuf[(wid * 16 + l16) * 136 + c * 32 + q * 8];
    f32x4 acc2[4];
#pragma unroll
    for (int u = 0; u < 4; u++) {
        f32x4 z = {0.f, 0.f, 0.f, 0.f};
#pragma unroll
        for (int c = 0; c < 4; c++) {
            bf16x8 wf = *(const bf16x8*)(const void*)&wt2[(u * 16 + l16) * 136 + c * 32 + q * 8];
            z = __builtin_amdgcn_mfma_f32_16x16x32_bf16(a2[c], wf, z, 0, 0, 0);
        }
        acc2[u] = z;
    }
#pragma unroll
    for (int u = 0; u < 4; u++) {
        int col = u * 16 + l16;
        float bc = B2[col];
#pragma unroll
        for (int r = 0; r < 4; r++) {
            int node = m0 + q * 4 + r;
            if (node < NN) {
                float val = acc2[u][r] + bc;
                if (OUTfp) OUTfp[(size_t)node * HD + col] = val;
                OUTbf[(size_t)node * HD + col] = (u16)f2bf(val);
            }
        }
    }
}

// ---------------- fused tail ----------------
__global__ __launch_bounds__(256) void k_final(const float* __restrict__ X1,
                                               const u16* __restrict__ H2bf,
                                               const float* __restrict__ LG,
                                               const float* __restrict__ LB,
                                               const float* __restrict__ NG,
                                               const float* __restrict__ NB_,
                                               const float* __restrict__ LW,
                                               const float* __restrict__ LBias,
                                               float* __restrict__ out) {
    int t = threadIdx.x;
    int lane = t & 63, wid = t >> 6;
    int n = blockIdx.x * 4 + wid;
    if (n >= NN) return;
    float x1v = X1[(size_t)n * HD + lane];
    float h2v = bf2f(H2bf[(size_t)n * HD + lane]);
    float s = wredsum(h2v);
    float qq = wredsum(h2v * h2v);
    float mu = s * (1.f / 64.f);
    float var = qq * (1.f / 64.f) - mu * mu;
    float hn = fmaxf((h2v - mu) * rsqrtf(var + 1e-5f) * LG[lane] + LB[lane], 0.f);
    float s2 = wredsum(x1v + hn);
    float q2 = wredsum(x1v * x1v + hn * hn);
    float mu2 = s2 * (1.f / 128.f);
    float var2 = q2 * (1.f / 128.f) - mu2 * mu2;
    float rs2 = rsqrtf(var2 + 1e-5f);
    float av = fmaxf((x1v - mu2) * rs2 * NG[lane] + NB_[lane], 0.f);
    float bv = fmaxf((hn - mu2) * rs2 * NG[64 + lane] + NB_[64 + lane], 0.f);
    float acc = av * LW[lane] + bv * LW[64 + lane];
    float tot = wredsum(acc);
    if (lane == 0) out[n] = tot + LBias[0];
}

extern "C" void kernel_launch(void* const* d_in, const int* in_sizes, int n_in,
                              void* d_out, int out_size, void* d_ws, size_t ws_size,
                              hipStream_t stream) {
    const float* x = (const float*)d_in[0];
    const int* ei = (const int*)d_in[1];
    const float* encW = (const float*)d_in[2];
    const float* encB = (const float*)d_in[3];
    const float* tptr = (const float*)d_in[4];
    const float* cW1 = (const float*)d_in[5];
    const float* cB1 = (const float*)d_in[6];
    const float* cG1 = (const float*)d_in[7];
    const float* cBE1 = (const float*)d_in[8];
    const float* cW2 = (const float*)d_in[9];
    const float* cB2 = (const float*)d_in[10];
    const float* ln1g = (const float*)d_in[11];
    const float* ln1b = (const float*)d_in[12];
    const float* ng = (const float*)d_in[13];
    const float* nb = (const float*)d_in[14];
    const float* lw = (const float*)d_in[15];
    const float* lb = (const float*)d_in[16];

    char* w = (char*)d_ws;
    size_t off = 0;
    auto carve = [&](size_t bytes) {
        void* p = w + off;
        off += (bytes + 255) & ~(size_t)255;
        return p;
    };
    int* flag = (int*)carve(4);
    int* rowptr = (int*)carve((NN + 1) * 4);
    int* cnt = (int*)carve((size_t)NN * 4);
    int* bsum = (int*)carve(NB * 4);
    u16* src16 = (u16*)carve((size_t)EE * 2);
    u16* dst16 = (u16*)carve((size_t)EE * 2);
    u16* eSrc = (u16*)carve((size_t)EE * 2);
    u16* Abf = (u16*)carve((size_t)NN * HD * 2);
    u16* AGbf = (u16*)carve((size_t)NN * HD * 2);
    float* X1 = (float*)carve((size_t)NN * HD * 4);
    u16* X1bf = (u16*)carve((size_t)NN * HD * 2);
    u16* H2bf = Abf;  // Abf dead after agg1

    hipMemsetAsync(flag, 0, 4, stream);
    k_detect<<<NB, 256, 0, stream>>>(ei, flag, cnt);  // probes layout + zeroes cnt
    k_hist<<<(EE + 255) / 256, 256, 0, stream>>>(ei, flag, cnt, src16, dst16);
    k_scan1<<<NB, 256, 0, stream>>>(cnt, rowptr, bsum);
    k_scan2<<<1, 256, 0, stream>>>(bsum);
    k_scan3<<<NB, 256, 0, stream>>>(bsum, rowptr, cnt);  // also re-zeroes cnt
    k_scatter<<<(EE + 255) / 256, 256, 0, stream>>>(src16, dst16, rowptr, cnt, eSrc);

    const int GB = (NN + 63) / 64;  // 782
    k_enc<<<GB, 256, 0, stream>>>(x, encW, encB, Abf);

    // conv1
    k_agg<<<2048, 256, 0, stream>>>(Abf, nullptr, rowptr, eSrc, tptr, AGbf);
    k_mlp<<<GB, 256, 0, stream>>>(AGbf, cW1, cB1, cG1, cBE1, cW2, cB2, X1, X1bf);
    // conv2 (shared weights)
    k_agg<<<2048, 256, 0, stream>>>(X1bf, X1, rowptr, eSrc, tptr, AGbf);
    k_mlp<<<GB, 256, 0, stream>>>(AGbf, cW1, cB1, cG1, cBE1, cW2, cB2, nullptr, H2bf);

    k_final<<<(NN + 3) / 4, 256, 0, stream>>>(X1, H2bf, ln1g, ln1b, ng, nb, lw, lb,
                                              (float*)d_out);
}

// Round 7
// 286.230 us; speedup vs baseline: 1.6332x; 1.1376x over previous
//
#include <hip/hip_runtime.h>
#include <hip/hip_bf16.h>

// DeeperGCN round-6: dispatch-count + gather-width attack.
// 13 -> 9 dispatches: detect computes flag in-kernel (no memset), scan1 re-zeroes
// cnt, scan3 dropped (rowptr = rowptrL + bsumP[i>>8] inline), scatter+enc merged,
// final fused into conv2 MLP epilogue. k_agg: 2 edges/gather-instruction via
// u32 channel-pair loads (lane = half x chanpair), shfl_xor(32) merge.

#define NN 50000
#define EE 800000
#define FIN 128
#define HD 64
#define NB 196       // scan blocks: 196*256 = 50176 >= NN+1
#define SCATB 3125   // scatter blocks: 3125*256 >= EE

typedef unsigned short u16;
typedef unsigned int u32;
using bf16x8 = __attribute__((ext_vector_type(8))) short;
using f32x4 = __attribute__((ext_vector_type(4))) float;

__device__ __forceinline__ float bf2f(u16 u) {
    u32 x = ((u32)u) << 16;
    float f;
    __builtin_memcpy(&f, &x, 4);
    return f;
}
__device__ __forceinline__ short f2bf(float f) {
    u32 u;
    __builtin_memcpy(&u, &f, 4);
    u32 r = (u + 0x7fffu + ((u >> 16) & 1u)) >> 16;  // RNE
    return (short)r;
}

// ---------------- detect (flag via block-0 reduction; zero cnt) ----------------
__global__ __launch_bounds__(256) void k_detect(const int* __restrict__ ei,
                                                int* __restrict__ flag,
                                                int* __restrict__ cnt) {
    __shared__ int red[256];
    int t = threadIdx.x;
    if (blockIdx.x == 0) {
        int any = 0;
#pragma unroll
        for (int k = 0; k < 4; k++) any |= (ei[2 * (t * 4 + k) + 1] != 0) ? 1 : 0;
        red[t] = any;
        __syncthreads();
        for (int d = 128; d >= 1; d >>= 1) {
            if (t < d) red[t] |= red[t + d];
            __syncthreads();
        }
        if (t == 0) *flag = red[0];  // 1 => int32 layout
    }
    int i = blockIdx.x * 256 + t;
    if (i < NN) cnt[i] = 0;
}
__device__ __forceinline__ int eidx_src(const int* ei, int e, int is32) {
    return is32 ? ei[e] : ei[2 * e];
}
__device__ __forceinline__ int eidx_dst(const int* ei, int e, int is32) {
    return is32 ? ei[EE + e] : ei[2 * (EE + e)];
}

// ---------------- hist: count + extract u16 src/dst ----------------
__global__ void k_hist(const int* __restrict__ ei, const int* __restrict__ flag,
                       int* __restrict__ cnt, u16* __restrict__ src16,
                       u16* __restrict__ dst16) {
    int e = blockIdx.x * blockDim.x + threadIdx.x;
    if (e >= EE) return;
    int is32 = *flag;
    int s = eidx_src(ei, e, is32);
    int d = eidx_dst(ei, e, is32);
    src16[e] = (u16)s;
    dst16[e] = (u16)d;
    atomicAdd(&cnt[d], 1);
}

// scan1: per-block exclusive prefix (rowptrL) + block sums; re-zero cnt for scatter
__global__ __launch_bounds__(256) void k_scan1(int* __restrict__ cnt,
                                               int* __restrict__ rowptrL,
                                               int* __restrict__ bsum) {
    __shared__ int ts[256];
    int t = threadIdx.x;
    int idx = blockIdx.x * 256 + t;
    int v = (idx < NN) ? cnt[idx] : 0;
    ts[t] = v;
    __syncthreads();
#pragma unroll
    for (int d = 1; d < 256; d <<= 1) {
        int u = (t >= d) ? ts[t - d] : 0;
        __syncthreads();
        ts[t] += u;
        __syncthreads();
    }
    if (idx <= NN) rowptrL[idx] = ts[t] - v;
    if (idx < NN) cnt[idx] = 0;
    if (t == 255) bsum[blockIdx.x] = ts[255];
}

// scan2: exclusive scan of 196 block sums (single block)
__global__ __launch_bounds__(256) void k_scan2(int* __restrict__ bsum) {
    __shared__ int ts[256];
    int t = threadIdx.x;
    int v = (t < NB) ? bsum[t] : 0;
    ts[t] = v;
    __syncthreads();
#pragma unroll
    for (int d = 1; d < 256; d <<= 1) {
        int u = (t >= d) ? ts[t - d] : 0;
        __syncthreads();
        ts[t] += u;
        __syncthreads();
    }
    if (t < NB) bsum[t] = ts[t] - v;
}

// ---------------- merged scatter + encoder ----------------
__global__ __launch_bounds__(256) void k_scatter_enc(
    const u16* __restrict__ src16, const u16* __restrict__ dst16,
    const int* __restrict__ rowptrL, const int* __restrict__ bsumP,
    int* __restrict__ cnt, u16* __restrict__ eSrc, const float* __restrict__ x,
    const float* __restrict__ W, const float* __restrict__ b, u16* __restrict__ Abf) {
    __shared__ short wtE[64 * 136];
    if (blockIdx.x < SCATB) {
        int e = blockIdx.x * 256 + threadIdx.x;
        if (e < EE) {
            int d = dst16[e];
            int p = atomicAdd(&cnt[d], 1);
            eSrc[rowptrL[d] + bsumP[d >> 8] + p] = src16[e];
        }
        return;
    }
    // encoder: Abf[n,0:64] = bf16(x[n,0:128] @ W + b)
    int tid = threadIdx.x;
    for (int i = tid; i < FIN * HD; i += 256) wtE[(i & 63) * 136 + (i >> 6)] = f2bf(W[i]);
    __syncthreads();

    int lane = tid & 63, wid = tid >> 6;
    int l16 = lane & 15, q = lane >> 4;
    int m0 = (int)(blockIdx.x - SCATB) * 64 + wid * 16;
    int mrow = m0 + l16;
    if (mrow >= NN) mrow = NN - 1;

    bf16x8 af[4];
#pragma unroll
    for (int c = 0; c < 4; c++) {
        const float4* p = (const float4*)(x + (size_t)mrow * FIN + c * 32 + q * 8);
        float4 p0 = p[0], p1 = p[1];
        af[c][0] = f2bf(p0.x); af[c][1] = f2bf(p0.y); af[c][2] = f2bf(p0.z); af[c][3] = f2bf(p0.w);
        af[c][4] = f2bf(p1.x); af[c][5] = f2bf(p1.y); af[c][6] = f2bf(p1.z); af[c][7] = f2bf(p1.w);
    }
    f32x4 acc[4];
#pragma unroll
    for (int u = 0; u < 4; u++) {
        f32x4 z = {0.f, 0.f, 0.f, 0.f};
#pragma unroll
        for (int c = 0; c < 4; c++) {
            bf16x8 wf = *(const bf16x8*)(const void*)&wtE[(u * 16 + l16) * 136 + c * 32 + q * 8];
            z = __builtin_amdgcn_mfma_f32_16x16x32_bf16(af[c], wf, z, 0, 0, 0);
        }
        acc[u] = z;
    }
#pragma unroll
    for (int u = 0; u < 4; u++) {
        int col = u * 16 + l16;
        float bc = b[col];
#pragma unroll
        for (int r = 0; r < 4; r++) {
            int node = m0 + q * 4 + r;
            if (node < NN) Abf[(size_t)node * HD + col] = (u16)f2bf(acc[u][r] + bc);
        }
    }
}

// ---------------- softmax aggregation: 2 edges per gather instruction ----------------
// lane = (half = lane>>5, cp = lane&31); lane reads channels {2cp, 2cp+1} (u32);
// half h processes CSR slots s+h, s+h+2, ...; shfl_xor(32) merges halves.
__global__ __launch_bounds__(256) void k_agg(const u16* __restrict__ Xbf,
                                             const float* __restrict__ Xfp,  // self (may be null)
                                             const int* __restrict__ rowptrL,
                                             const int* __restrict__ bsumP,
                                             const u16* __restrict__ eSrc,
                                             const float* __restrict__ tptr,
                                             u16* __restrict__ OUTbf) {
    int t = threadIdx.x;
    int lane = t & 63, wid = t >> 6;
    int half = lane >> 5, cp = lane & 31;
    float tt = tptr[0];
    for (int n = blockIdx.x * 4 + wid; n < NN; n += gridDim.x * 4) {
        int s = rowptrL[n] + bsumP[n >> 8];
        int e = rowptrL[n + 1] + bsumP[(n + 1) >> 8];
        float self0, self1;
        if (Xfp) {
            float2 f2 = *(const float2*)(Xfp + (size_t)n * HD + 2 * cp);
            self0 = f2.x; self1 = f2.y;
        } else {
            u32 u = *(const u32*)(const void*)(Xbf + (size_t)n * HD + 2 * cp);
            self0 = bf2f((u16)u); self1 = bf2f((u16)(u >> 16));
        }
        float num0 = 0.f, den0 = 0.f, num1 = 0.f, den1 = 0.f;
        int base = s;
        for (; base + 8 <= e; base += 8) {
#pragma unroll
            for (int k = 0; k < 4; k++) {
                int idx = base + 2 * k + half;
                int sv = eSrc[idx];
                u32 u = *(const u32*)(const void*)(Xbf + (size_t)sv * HD + 2 * cp);
                float m0 = fmaxf(bf2f((u16)u), 0.f) + 1e-7f;
                float m1 = fmaxf(bf2f((u16)(u >> 16)), 0.f) + 1e-7f;
                float p0 = __expf(m0 * tt);
                float p1 = __expf(m1 * tt);
                den0 += p0; num0 += m0 * p0;
                den1 += p1; num1 += m1 * p1;
            }
        }
        for (int i = base + half; i < e; i += 2) {
            int sv = eSrc[i];
            u32 u = *(const u32*)(const void*)(Xbf + (size_t)sv * HD + 2 * cp);
            float m0 = fmaxf(bf2f((u16)u), 0.f) + 1e-7f;
            float m1 = fmaxf(bf2f((u16)(u >> 16)), 0.f) + 1e-7f;
            float p0 = __expf(m0 * tt);
            float p1 = __expf(m1 * tt);
            den0 += p0; num0 += m0 * p0;
            den1 += p1; num1 += m1 * p1;
        }
        num0 += __shfl_xor(num0, 32, 64);
        den0 += __shfl_xor(den0, 32, 64);
        num1 += __shfl_xor(num1, 32, 64);
        den1 += __shfl_xor(den1, 32, 64);
        if (half == 0) {
            float a0 = num0 / (den0 + 1e-16f) + self0;
            float a1 = num1 / (den1 + 1e-16f) + self1;
            u32 pk = (u32)(u16)f2bf(a0) | ((u32)(u16)f2bf(a1) << 16);
            *(u32*)(void*)(OUTbf + (size_t)n * HD + 2 * cp) = pk;
        }
    }
}

// ---------------- conv1 MLP (MFMA): relu(LN(in@W1+b1))@W2+b2 -> X1 fp32 + bf16 ----------------
__global__ __launch_bounds__(256) void k_mlp(const u16* __restrict__ INbf,
                                             const float* __restrict__ W1,
                                             const float* __restrict__ B1,
                                             const float* __restrict__ G1,
                                             const float* __restrict__ BE1,
                                             const float* __restrict__ W2,
                                             const float* __restrict__ B2,
                                             float* __restrict__ OUTfp,
                                             u16* __restrict__ OUTbf) {
    __shared__ short wt1[128 * 72];
    __shared__ short wt2[64 * 136];
    __shared__ short hbuf[64 * 136];
    int tid = threadIdx.x;
    for (int i = tid; i < HD * 128; i += 256) wt1[(i & 127) * 72 + (i >> 7)] = f2bf(W1[i]);
    for (int i = tid; i < 128 * HD; i += 256) wt2[(i & 63) * 136 + (i >> 6)] = f2bf(W2[i]);
    __syncthreads();

    int lane = tid & 63, wid = tid >> 6;
    int l16 = lane & 15, q = lane >> 4;
    int m0 = blockIdx.x * 64 + wid * 16;
    int mrow = m0 + l16;
    if (mrow >= NN) mrow = NN - 1;

    float b1v[8], g1v[8], bev[8];
#pragma unroll
    for (int tl = 0; tl < 8; tl++) {
        int j = tl * 16 + l16;
        b1v[tl] = B1[j]; g1v[tl] = G1[j]; bev[tl] = BE1[j];
    }

    bf16x8 a0 = *(const bf16x8*)(const void*)(INbf + (size_t)mrow * HD + q * 8);
    bf16x8 a1 = *(const bf16x8*)(const void*)(INbf + (size_t)mrow * HD + 32 + q * 8);
    f32x4 acc1[8];
#pragma unroll
    for (int tl = 0; tl < 8; tl++) {
        bf16x8 w0 = *(const bf16x8*)(const void*)&wt1[(tl * 16 + l16) * 72 + q * 8];
        bf16x8 w1 = *(const bf16x8*)(const void*)&wt1[(tl * 16 + l16) * 72 + 32 + q * 8];
        f32x4 z = {0.f, 0.f, 0.f, 0.f};
        z = __builtin_amdgcn_mfma_f32_16x16x32_bf16(a0, w0, z, 0, 0, 0);
        z = __builtin_amdgcn_mfma_f32_16x16x32_bf16(a1, w1, z, 0, 0, 0);
        acc1[tl] = z;
    }
    float S[4] = {0, 0, 0, 0}, Q[4] = {0, 0, 0, 0};
#pragma unroll
    for (int tl = 0; tl < 8; tl++)
#pragma unroll
        for (int r = 0; r < 4; r++) {
            float v = acc1[tl][r] + b1v[tl];
            acc1[tl][r] = v;
            S[r] += v; Q[r] += v * v;
        }
#pragma unroll
    for (int m = 8; m >= 1; m >>= 1)
#pragma unroll
        for (int r = 0; r < 4; r++) {
            S[r] += __shfl_xor(S[r], m, 64);
            Q[r] += __shfl_xor(Q[r], m, 64);
        }
    float mu[4], rs[4];
#pragma unroll
    for (int r = 0; r < 4; r++) {
        mu[r] = S[r] * (1.f / 128.f);
        float var = Q[r] * (1.f / 128.f) - mu[r] * mu[r];
        rs[r] = rsqrtf(var + 1e-5f);
    }
#pragma unroll
    for (int tl = 0; tl < 8; tl++)
#pragma unroll
        for (int r = 0; r < 4; r++) {
            float h = fmaxf((acc1[tl][r] - mu[r]) * rs[r] * g1v[tl] + bev[tl], 0.f);
            hbuf[(wid * 16 + q * 4 + r) * 136 + tl * 16 + l16] = f2bf(h);
        }
    // wave-private LDS rows; per-wave DS ordering suffices

    bf16x8 a2[4];
#pragma unroll
    for (int c = 0; c < 4; c++)
        a2[c] = *(const bf16x8*)(const void*)&hbuf[(wid * 16 + l16) * 136 + c * 32 + q * 8];
    f32x4 acc2[4];
#pragma unroll
    for (int u = 0; u < 4; u++) {
        f32x4 z = {0.f, 0.f, 0.f, 0.f};
#pragma unroll
        for (int c = 0; c < 4; c++) {
            bf16x8 wf = *(const bf16x8*)(const void*)&wt2[(u * 16 + l16) * 136 + c * 32 + q * 8];
            z = __builtin_amdgcn_mfma_f32_16x16x32_bf16(a2[c], wf, z, 0, 0, 0);
        }
        acc2[u] = z;
    }
#pragma unroll
    for (int u = 0; u < 4; u++) {
        int col = u * 16 + l16;
        float bc = B2[col];
#pragma unroll
        for (int r = 0; r < 4; r++) {
            int node = m0 + q * 4 + r;
            if (node < NN) {
                float val = acc2[u][r] + bc;
                OUTfp[(size_t)node * HD + col] = val;
                OUTbf[(size_t)node * HD + col] = (u16)f2bf(val);
            }
        }
    }
}

// ---------------- conv2 MLP + fused tail: h2 -> relu(LN64) -> concat-LN128 -> lin ----------------
__global__ __launch_bounds__(256) void k_mlpfin(const u16* __restrict__ INbf,
                                                const float* __restrict__ W1,
                                                const float* __restrict__ B1,
                                                const float* __restrict__ G1,
                                                const float* __restrict__ BE1,
                                                const float* __restrict__ W2,
                                                const float* __restrict__ B2,
                                                const float* __restrict__ X1,
                                                const float* __restrict__ LG,
                                                const float* __restrict__ LB,
                                                const float* __restrict__ NG,
                                                const float* __restrict__ NBv,
                                                const float* __restrict__ LW,
                                                const float* __restrict__ LBias,
                                                float* __restrict__ out) {
    __shared__ short wt1[128 * 72];
    __shared__ short wt2[64 * 136];
    __shared__ short hbuf[64 * 136];
    int tid = threadIdx.x;
    for (int i = tid; i < HD * 128; i += 256) wt1[(i & 127) * 72 + (i >> 7)] = f2bf(W1[i]);
    for (int i = tid; i < 128 * HD; i += 256) wt2[(i & 63) * 136 + (i >> 6)] = f2bf(W2[i]);
    __syncthreads();

    int lane = tid & 63, wid = tid >> 6;
    int l16 = lane & 15, q = lane >> 4;
    int m0 = blockIdx.x * 64 + wid * 16;
    int mrow = m0 + l16;
    if (mrow >= NN) mrow = NN - 1;

    float b1v[8], g1v[8], bev[8];
#pragma unroll
    for (int tl = 0; tl < 8; tl++) {
        int j = tl * 16 + l16;
        b1v[tl] = B1[j]; g1v[tl] = G1[j]; bev[tl] = BE1[j];
    }

    bf16x8 a0 = *(const bf16x8*)(const void*)(INbf + (size_t)mrow * HD + q * 8);
    bf16x8 a1 = *(const bf16x8*)(const void*)(INbf + (size_t)mrow * HD + 32 + q * 8);
    f32x4 acc1[8];
#pragma unroll
    for (int tl = 0; tl < 8; tl++) {
        bf16x8 w0 = *(const bf16x8*)(const void*)&wt1[(tl * 16 + l16) * 72 + q * 8];
        bf16x8 w1 = *(const bf16x8*)(const void*)&wt1[(tl * 16 + l16) * 72 + 32 + q * 8];
        f32x4 z = {0.f, 0.f, 0.f, 0.f};
        z = __builtin_amdgcn_mfma_f32_16x16x32_bf16(a0, w0, z, 0, 0, 0);
        z = __builtin_amdgcn_mfma_f32_16x16x32_bf16(a1, w1, z, 0, 0, 0);
        acc1[tl] = z;
    }
    float S[4] = {0, 0, 0, 0}, Q[4] = {0, 0, 0, 0};
#pragma unroll
    for (int tl = 0; tl < 8; tl++)
#pragma unroll
        for (int r = 0; r < 4; r++) {
            float v = acc1[tl][r] + b1v[tl];
            acc1[tl][r] = v;
            S[r] += v; Q[r] += v * v;
        }
#pragma unroll
    for (int m = 8; m >= 1; m >>= 1)
#pragma unroll
        for (int r = 0; r < 4; r++) {
            S[r] += __shfl_xor(S[r], m, 64);
            Q[r] += __shfl_xor(Q[r], m, 64);
        }
#pragma unroll
    for (int r = 0; r < 4; r++) {
        float mu = S[r] * (1.f / 128.f);
        float var = Q[r] * (1.f / 128.f) - mu * mu;
        float rs = rsqrtf(var + 1e-5f);
        S[r] = mu; Q[r] = rs;  // reuse
    }
#pragma unroll
    for (int tl = 0; tl < 8; tl++)
#pragma unroll
        for (int r = 0; r < 4; r++) {
            float h = fmaxf((acc1[tl][r] - S[r]) * Q[r] * g1v[tl] + bev[tl], 0.f);
            hbuf[(wid * 16 + q * 4 + r) * 136 + tl * 16 + l16] = f2bf(h);
        }

    bf16x8 a2[4];
#pragma unroll
    for (int c = 0; c < 4; c++)
        a2[c] = *(const bf16x8*)(const void*)&hbuf[(wid * 16 + l16) * 136 + c * 32 + q * 8];
    f32x4 acc2[4];
#pragma unroll
    for (int u = 0; u < 4; u++) {
        f32x4 z = {0.f, 0.f, 0.f, 0.f};
#pragma unroll
        for (int c = 0; c < 4; c++) {
            bf16x8 wf = *(const bf16x8*)(const void*)&wt2[(u * 16 + l16) * 136 + c * 32 + q * 8];
            z = __builtin_amdgcn_mfma_f32_16x16x32_bf16(a2[c], wf, z, 0, 0, 0);
        }
        acc2[u] = z;
    }

    // ---- fused tail. h2[u][r] = acc2[u][r] + B2[col], col = u*16+l16 ----
    float lg[4], lbv[4], ng1[4], nb1[4], ng2[4], nb2[4], lw1[4], lw2[4], b2c[4];
#pragma unroll
    for (int u = 0; u < 4; u++) {
        int col = u * 16 + l16;
        b2c[u] = B2[col];
        lg[u] = LG[col]; lbv[u] = LB[col];
        ng1[u] = NG[col]; nb1[u] = NBv[col];
        ng2[u] = NG[64 + col]; nb2[u] = NBv[64 + col];
        lw1[u] = LW[col]; lw2[u] = LW[64 + col];
    }
    float lbias0 = LBias[0];

    float h2[4][4];
    float Sh[4] = {0, 0, 0, 0}, Qh[4] = {0, 0, 0, 0};
#pragma unroll
    for (int u = 0; u < 4; u++)
#pragma unroll
        for (int r = 0; r < 4; r++) {
            float v = acc2[u][r] + b2c[u];
            h2[u][r] = v;
            Sh[r] += v; Qh[r] += v * v;
        }
#pragma unroll
    for (int m = 8; m >= 1; m >>= 1)
#pragma unroll
        for (int r = 0; r < 4; r++) {
            Sh[r] += __shfl_xor(Sh[r], m, 64);
            Qh[r] += __shfl_xor(Qh[r], m, 64);
        }
    float hn[4][4], x1v[4][4];
    float S2[4] = {0, 0, 0, 0}, Q2[4] = {0, 0, 0, 0};
#pragma unroll
    for (int r = 0; r < 4; r++) {
        float mu = Sh[r] * (1.f / 64.f);
        float var = Qh[r] * (1.f / 64.f) - mu * mu;
        float rs = rsqrtf(var + 1e-5f);
        int node = m0 + q * 4 + r;
        int nodeC = node < NN ? node : NN - 1;
#pragma unroll
        for (int u = 0; u < 4; u++) {
            float h = fmaxf((h2[u][r] - mu) * rs * lg[u] + lbv[u], 0.f);
            hn[u][r] = h;
            float xv = X1[(size_t)nodeC * HD + u * 16 + l16];
            x1v[u][r] = xv;
            S2[r] += xv + h;
            Q2[r] += xv * xv + h * h;
        }
    }
#pragma unroll
    for (int m = 8; m >= 1; m >>= 1)
#pragma unroll
        for (int r = 0; r < 4; r++) {
            S2[r] += __shfl_xor(S2[r], m, 64);
            Q2[r] += __shfl_xor(Q2[r], m, 64);
        }
    float contrib[4];
#pragma unroll
    for (int r = 0; r < 4; r++) {
        float mu2 = S2[r] * (1.f / 128.f);
        float var2 = Q2[r] * (1.f / 128.f) - mu2 * mu2;
        float rs2 = rsqrtf(var2 + 1e-5f);
        float c = 0.f;
#pragma unroll
        for (int u = 0; u < 4; u++) {
            float av = fmaxf((x1v[u][r] - mu2) * rs2 * ng1[u] + nb1[u], 0.f);
            float bv = fmaxf((hn[u][r] - mu2) * rs2 * ng2[u] + nb2[u], 0.f);
            c += av * lw1[u] + bv * lw2[u];
        }
        contrib[r] = c;
    }
#pragma unroll
    for (int m = 8; m >= 1; m >>= 1)
#pragma unroll
        for (int r = 0; r < 4; r++) contrib[r] += __shfl_xor(contrib[r], m, 64);
    if (l16 == 0) {
#pragma unroll
        for (int r = 0; r < 4; r++) {
            int node = m0 + q * 4 + r;
            if (node < NN) out[node] = contrib[r] + lbias0;
        }
    }
}

extern "C" void kernel_launch(void* const* d_in, const int* in_sizes, int n_in,
                              void* d_out, int out_size, void* d_ws, size_t ws_size,
                              hipStream_t stream) {
    const float* x = (const float*)d_in[0];
    const int* ei = (const int*)d_in[1];
    const float* encW = (const float*)d_in[2];
    const float* encB = (const float*)d_in[3];
    const float* tptr = (const float*)d_in[4];
    const float* cW1 = (const float*)d_in[5];
    const float* cB1 = (const float*)d_in[6];
    const float* cG1 = (const float*)d_in[7];
    const float* cBE1 = (const float*)d_in[8];
    const float* cW2 = (const float*)d_in[9];
    const float* cB2 = (const float*)d_in[10];
    const float* ln1g = (const float*)d_in[11];
    const float* ln1b = (const float*)d_in[12];
    const float* ng = (const float*)d_in[13];
    const float* nb = (const float*)d_in[14];
    const float* lw = (const float*)d_in[15];
    const float* lb = (const float*)d_in[16];

    char* w = (char*)d_ws;
    size_t off = 0;
    auto carve = [&](size_t bytes) {
        void* p = w + off;
        off += (bytes + 255) & ~(size_t)255;
        return p;
    };
    int* flag = (int*)carve(4);
    int* rowptrL = (int*)carve((NN + 1) * 4);
    int* cnt = (int*)carve((size_t)NN * 4);
    int* bsum = (int*)carve(NB * 4);
    u16* src16 = (u16*)carve((size_t)EE * 2);
    u16* dst16 = (u16*)carve((size_t)EE * 2);
    u16* eSrc = (u16*)carve((size_t)EE * 2);
    u16* Abf = (u16*)carve((size_t)NN * HD * 2);
    u16* AGbf = (u16*)carve((size_t)NN * HD * 2);
    float* X1 = (float*)carve((size_t)NN * HD * 4);
    u16* X1bf = (u16*)carve((size_t)NN * HD * 2);

    k_detect<<<NB, 256, 0, stream>>>(ei, flag, cnt);
    k_hist<<<SCATB, 256, 0, stream>>>(ei, flag, cnt, src16, dst16);
    k_scan1<<<NB, 256, 0, stream>>>(cnt, rowptrL, bsum);  // also re-zeroes cnt
    k_scan2<<<1, 256, 0, stream>>>(bsum);

    const int GB = (NN + 63) / 64;  // 782
    k_scatter_enc<<<SCATB + GB, 256, 0, stream>>>(src16, dst16, rowptrL, bsum, cnt, eSrc,
                                                  x, encW, encB, Abf);

    // conv1
    k_agg<<<2048, 256, 0, stream>>>(Abf, nullptr, rowptrL, bsum, eSrc, tptr, AGbf);
    k_mlp<<<GB, 256, 0, stream>>>(AGbf, cW1, cB1, cG1, cBE1, cW2, cB2, X1, X1bf);
    // conv2 (shared weights) + fused tail
    k_agg<<<2048, 256, 0, stream>>>(X1bf, X1, rowptrL, bsum, eSrc, tptr, AGbf);
    k_mlpfin<<<GB, 256, 0, stream>>>(AGbf, cW1, cB1, cG1, cBE1, cW2, cB2, X1,
                                     ln1g, ln1b, ng, nb, lw, lb, (float*)d_out);
}